// Round 7
// baseline (6109.075 us; speedup 1.0000x reference)
//
#include <hip/hip_runtime.h>
#include <hip/hip_bf16.h>

#define VV 32000
#define EE 256
#define HH 512
#define BB 64
#define TT 64
#define SS 64
#define G3 1536   // 3*H
#define NBLK 256
#define STSZ (HH * BB)   // one state buffer, floats

typedef __attribute__((ext_vector_type(8))) short bf16x8;
typedef __attribute__((ext_vector_type(4))) float f32x4;

__device__ __forceinline__ void async16(void* lds, const void* g) {
  __builtin_amdgcn_global_load_lds((const __attribute__((address_space(1))) void*)g,
                                   (__attribute__((address_space(3))) void*)lds, 16, 0, 0);
}

__device__ __forceinline__ float sigmoid_fast(float x) {
  return 1.0f / (1.0f + __expf(-x));
}
__device__ __forceinline__ float tanh_fast(float x) {
  x = fminf(fmaxf(x, -15.f), 15.f);
  float e = __expf(2.f * x);
  return (e - 1.f) / (e + 1.f);
}

// coherent store: write-through past L2 to the IF coherence point (no fence needed)
__device__ __forceinline__ void stg_sc(float* p, float v) {
  asm volatile("global_store_dword %0, %1, off sc0 sc1" :: "v"(p), "v"(v) : "memory");
}
// non-temporal load: evict-first in L2 (protects resident read-only data)
__device__ __forceinline__ float ldnt(const float* p) {
  return __builtin_nontemporal_load(p);
}

// fence-free one-shot grid barrier: syncthreads drains each wave's vmcnt (sc stores
// acked at coherence point), then a single relaxed agent atomic per block.
__device__ __forceinline__ void gbar(int* bar, int idx) {
  __syncthreads();
  if (threadIdx.x == 0) {
    __hip_atomic_fetch_add(&bar[idx], 1, __ATOMIC_RELAXED, __HIP_MEMORY_SCOPE_AGENT);
    while (__hip_atomic_load(&bar[idx], __ATOMIC_RELAXED, __HIP_MEMORY_SCOPE_AGENT) < NBLK)
      __builtin_amdgcn_s_sleep(1);
  }
  __syncthreads();
}

// ---------------- strided 2D transpose: dst[c][r] = src[r*ld + off + c]
__global__ __launch_bounds__(256) void transpose_kernel(float* __restrict__ dst,
                                                        const float* __restrict__ src,
                                                        int R, int C, int ld, int off) {
  __shared__ float tile[32][33];
  int c0 = blockIdx.x * 32, r0 = blockIdx.y * 32;
  int x = threadIdx.x, y = threadIdx.y;     // block (32,8)
  for (int i = y; i < 32; i += 8) tile[i][x] = src[(size_t)(r0 + i) * ld + off + c0 + x];
  __syncthreads();
  for (int i = y; i < 32; i += 8) dst[(size_t)(c0 + i) * R + r0 + x] = tile[x][i];
}

// ---------------- fp32 -> bf16 cast
__global__ __launch_bounds__(256) void cast_kernel(const float* __restrict__ src,
                                                   __hip_bfloat16* __restrict__ dst, int n) {
  for (int i = blockIdx.x * blockDim.x + threadIdx.x; i < n; i += gridDim.x * blockDim.x)
    dst[i] = __float2bfloat16(src[i]);
}

// ---------------- transpose initial hidden state into [h][b] layout
__global__ __launch_bounds__(256) void hsT_kernel(const float* __restrict__ hs,
                                                  float* __restrict__ h0T,
                                                  float* __restrict__ h1T) {
  int i = blockIdx.x * 256 + threadIdx.x;   // 0..32767
  int b = i >> 9, h = i & 511;
  h0T[h * BB + b] = hs[b * HH + h];
  h1T[h * BB + b] = hs[BB * HH + b * HH + h];
}

// ---------------- tiled fp32 GEMM: C = A(row-gathered) * Bk (+bias)
// tbmaj==0: C[m][n];  tbmaj==1: C[(m>>6)][n][m&63]  (i.e. [t][n][b] for m=t*64+b)
__global__ __launch_bounds__(256) void gemm32_kernel(const float* __restrict__ A,
                                                     const int* __restrict__ Xtb,
                                                     const float* __restrict__ Bk,
                                                     const float* __restrict__ bias,
                                                     float* __restrict__ C,
                                                     int N, int K, int ldb, int tbmaj) {
  __shared__ float Xs[32][65];    // [k][m]
  __shared__ float Ws[32][129];   // [k][n]
  __shared__ int toks[64];
  int m0 = blockIdx.x * 64, n0 = blockIdx.y * 128;
  int tid = threadIdx.x;
  if (tid < 64) {
    int m = m0 + tid;
    toks[tid] = Xtb ? Xtb[(m & 63) * TT + (m >> 6)] : m;
  }
  __syncthreads();
  float acc[4][8];
#pragma unroll
  for (int i = 0; i < 4; ++i)
#pragma unroll
    for (int j = 0; j < 8; ++j) acc[i][j] = 0.f;
  int mi = (tid >> 4) * 4;   // 4 m per thread
  int ni = (tid & 15) * 8;   // 8 n per thread
  for (int kc = 0; kc < K; kc += 32) {
#pragma unroll
    for (int i = 0; i < 16; ++i) {
      int idx = tid + i * 256;          // 0..4095
      int kk = idx >> 7, nn = idx & 127;
      Ws[kk][nn] = Bk[(size_t)(kc + kk) * ldb + n0 + nn];
    }
#pragma unroll
    for (int i = 0; i < 8; ++i) {
      int idx = tid + i * 256;          // 0..2047
      int mm = idx >> 5, kk = idx & 31;
      Xs[kk][mm] = A[(size_t)toks[mm] * K + kc + kk];
    }
    __syncthreads();
#pragma unroll
    for (int k = 0; k < 32; ++k) {
      float xv[4], wv[8];
#pragma unroll
      for (int i = 0; i < 4; ++i) xv[i] = Xs[k][mi + i];
#pragma unroll
      for (int j = 0; j < 8; ++j) wv[j] = Ws[k][ni + j];
#pragma unroll
      for (int i = 0; i < 4; ++i)
#pragma unroll
        for (int j = 0; j < 8; ++j) acc[i][j] += xv[i] * wv[j];
    }
    __syncthreads();
  }
#pragma unroll
  for (int i = 0; i < 4; ++i) {
    int m = m0 + mi + i;
#pragma unroll
    for (int j = 0; j < 8; ++j) {
      int n = n0 + ni + j;
      float v = acc[i][j] + (bias ? bias[n] : 0.f);
      if (tbmaj) C[((size_t)(m >> 6) * N + n) * BB + (m & 63)] = v;
      else       C[(size_t)m * N + n] = v;
    }
  }
}

// ---------------- persistent recurrent kernel (256 blocks x 1024 threads, 16 waves)
// Per step, 4 phases / 4 barriers:
//  alpha: q-proj (blocks 0-63, waves 0-7, 8 j-cols each)  ||  Wh0*h0p (waves 8-11)
//         and Wh1*h1p (waves 12-15) partials in ALL blocks (overlapped with q).
//  beta : attention scores+softmax+context (blocks 0-63).
//  gamma: Wi0*ctx (waves 0-7) + combine with Wh0 partials -> h0n.
//  delta: Wi1*h0n (waves 0-7) + combine with Wh1 partials -> h1n + bf16 outs.
// Weights LDS-resident; state [k][b] one-shot buffers, sc0sc1 stores, nt reads.
struct RecArgs {
  const float *Wq, *W_ih0, *W_hh0, *W_ih1, *W_hh1;
  const float *b_hh0, *b_ih1, *b_hh1;
  const float *gixT, *keysp, *enc, *wv;   // gixT: [t][j(1536)][b]
  const int* vlen;
  const float *h0init, *h1init;     // [k][b]
  float *qS;                        // [TT][b][j]  one-shot
  float *ctxS, *h0S, *h1S;          // [TT][k][b]  one-shot
  int* bar;
  __hip_bfloat16* outsb;
};

__global__ __launch_bounds__(1024) void recurrent_kernel(RecArgs a) {
  const int blk = blockIdx.x, tid = threadIdx.x;
  const int w = tid >> 6, lane = tid & 63;
  const int j0g = 2 * blk;        // GRU output cols
  const int jq0 = 8 * blk;        // q output cols (blocks 0-63)

  __shared__ __align__(16) float WL0[6][1024];   // r0,r1,z0,z1,n0,n1; k<512 Wi, k>=512 Wh
  __shared__ __align__(16) float WL1[6][1024];
  __shared__ __align__(16) float QL[8][512];     // Wq rows jq0..jq0+7 (blocks<64)
  __shared__ float redq[8][8][64];
  __shared__ float wh0p[6][4][64];
  __shared__ float wh1p[6][4][64];
  __shared__ float wi[6][8][64];
  __shared__ float sQ[HH], sWV[HH], sAttn[SS];

  // one-time weight preload (rows of original matrices are contiguous)
  for (int idx = tid; idx < 6 * 1024; idx += 1024) {
    int s = idx >> 10, k = idx & 1023;
    int g = s >> 1, jj = s & 1;
    int r = g * 512 + j0g + jj;
    WL0[s][k] = (k < 512) ? a.W_ih0[(size_t)r * 768 + k] : a.W_hh0[(size_t)r * 512 + (k - 512)];
    WL1[s][k] = (k < 512) ? a.W_ih1[(size_t)r * 512 + k] : a.W_hh1[(size_t)r * 512 + (k - 512)];
  }
  if (blk < BB) {
    for (int idx = tid; idx < 8 * 512; idx += 1024) {
      int jj = idx >> 9, k = idx & 511;
      QL[jj][k] = a.Wq[(size_t)(jq0 + jj) * HH + k];
    }
  }
  if (tid < 512) sWV[tid] = a.wv[tid];
  const int vl = (blk < BB) ? a.vlen[blk] : 0;
  __syncthreads();

  for (int t = 0; t < TT; ++t) {
    const float* h0p = (t == 0) ? a.h0init : a.h0S + (size_t)(t - 1) * STSZ;
    const float* h1p = (t == 0) ? a.h1init : a.h1S + (size_t)(t - 1) * STSZ;
    float* qrow = a.qS + (size_t)t * BB * HH;    // [b][j]
    float* ctxt = a.ctxS + (size_t)t * STSZ;
    float* h0n  = a.h0S + (size_t)t * STSZ;
    float* h1n  = a.h1S + (size_t)t * STSZ;

    // ================= phase alpha =================
    if (w >= 8) {
      // Wh partials (all blocks): waves 8-11 -> layer0, 12-15 -> layer1
      const int layer = (w >= 12) ? 1 : 0;
      const float* Hp = layer ? h1p : h0p;
      const float (*WL)[1024] = layer ? WL1 : WL0;
      const int wq = w & 3;
      const int kb = wq * 128;
      const float* xp = Hp + (size_t)kb * BB + lane;
      float s0 = 0, s1 = 0, s2 = 0, s3 = 0, s4 = 0, s5 = 0;
#pragma unroll 8
      for (int k = 0; k < 128; k += 4) {
        float x0 = ldnt(xp + (k + 0) * BB);
        float x1 = ldnt(xp + (k + 1) * BB);
        float x2 = ldnt(xp + (k + 2) * BB);
        float x3 = ldnt(xp + (k + 3) * BB);
        float4 w0 = *(const float4*)&WL[0][512 + kb + k];
        float4 w1 = *(const float4*)&WL[1][512 + kb + k];
        float4 w2 = *(const float4*)&WL[2][512 + kb + k];
        float4 w3 = *(const float4*)&WL[3][512 + kb + k];
        float4 w4 = *(const float4*)&WL[4][512 + kb + k];
        float4 w5 = *(const float4*)&WL[5][512 + kb + k];
        s0 += w0.x * x0 + w0.y * x1 + w0.z * x2 + w0.w * x3;
        s1 += w1.x * x0 + w1.y * x1 + w1.z * x2 + w1.w * x3;
        s2 += w2.x * x0 + w2.y * x1 + w2.z * x2 + w2.w * x3;
        s3 += w3.x * x0 + w3.y * x1 + w3.z * x2 + w3.w * x3;
        s4 += w4.x * x0 + w4.y * x1 + w4.z * x2 + w4.w * x3;
        s5 += w5.x * x0 + w5.y * x1 + w5.z * x2 + w5.w * x3;
      }
      float (*whp)[4][64] = layer ? wh1p : wh0p;
      whp[0][wq][lane] = s0; whp[1][wq][lane] = s1;
      whp[2][wq][lane] = s2; whp[3][wq][lane] = s3;
      whp[4][wq][lane] = s4; whp[5][wq][lane] = s5;
    } else if (blk < BB) {
      // q-projection: 8 j-cols, k-split over waves 0-7
      const int kb = w * 64;
      const float* xp = h1p + (size_t)kb * BB + lane;
      float q0 = 0, q1 = 0, q2 = 0, q3 = 0, q4 = 0, q5 = 0, q6 = 0, q7 = 0;
#pragma unroll 8
      for (int k = 0; k < 64; k += 2) {
        float x0 = ldnt(xp + (k + 0) * BB);
        float x1 = ldnt(xp + (k + 1) * BB);
        float2 a0 = *(const float2*)&QL[0][kb + k];
        float2 a1 = *(const float2*)&QL[1][kb + k];
        float2 a2 = *(const float2*)&QL[2][kb + k];
        float2 a3 = *(const float2*)&QL[3][kb + k];
        float2 a4 = *(const float2*)&QL[4][kb + k];
        float2 a5 = *(const float2*)&QL[5][kb + k];
        float2 a6 = *(const float2*)&QL[6][kb + k];
        float2 a7 = *(const float2*)&QL[7][kb + k];
        q0 += a0.x * x0 + a0.y * x1;  q1 += a1.x * x0 + a1.y * x1;
        q2 += a2.x * x0 + a2.y * x1;  q3 += a3.x * x0 + a3.y * x1;
        q4 += a4.x * x0 + a4.y * x1;  q5 += a5.x * x0 + a5.y * x1;
        q6 += a6.x * x0 + a6.y * x1;  q7 += a7.x * x0 + a7.y * x1;
      }
      redq[0][w][lane] = q0; redq[1][w][lane] = q1;
      redq[2][w][lane] = q2; redq[3][w][lane] = q3;
      redq[4][w][lane] = q4; redq[5][w][lane] = q5;
      redq[6][w][lane] = q6; redq[7][w][lane] = q7;
    }
    __syncthreads();
    if (blk < BB && tid < 512) {
      int b = tid >> 3, j = tid & 7;    // 8 consecutive j per b -> packed 32B sectors
      float v = 0.f;
#pragma unroll
      for (int q = 0; q < 8; ++q) v += redq[j][q][b];
      stg_sc(&qrow[(size_t)b * HH + jq0 + j], v);
    }
    gbar(a.bar, t * 4 + 0);

    // ================= phase beta: attention =================
    if (blk < BB) {
      const int b = blk;
      if (tid < 512) sQ[tid] = qrow[(size_t)b * HH + tid];   // coalesced, one-shot
      __syncthreads();
      for (int s = w; s < SS; s += 16) {
        const float* kp = a.keysp + ((size_t)b * SS + s) * HH;
        float p = 0.f;
#pragma unroll
        for (int h = lane; h < HH; h += 64)
          p += tanh_fast(sQ[h] + kp[h]) * sWV[h];
#pragma unroll
        for (int off = 32; off > 0; off >>= 1) p += __shfl_down(p, off);
        if (lane == 0) sAttn[s] = (s < vl) ? p : -1e6f;
      }
      __syncthreads();
      if (w == 0) {
        float v = sAttn[lane];
        float mx = v;
        for (int off = 32; off > 0; off >>= 1) mx = fmaxf(mx, __shfl_xor(mx, off));
        float e = __expf(v - mx);
        float sm = e;
        for (int off = 32; off > 0; off >>= 1) sm += __shfl_xor(sm, off);
        sAttn[lane] = e / sm;
      }
      __syncthreads();
      if (tid < 512) {
        float c = 0.f;
#pragma unroll 8
        for (int s = 0; s < SS; ++s) c += sAttn[s] * a.enc[((size_t)b * SS + s) * HH + tid];
        stg_sc(&ctxt[(size_t)tid * BB + b], c);
      }
    }
    gbar(a.bar, t * 4 + 1);

    // ================= phase gamma: GRU0 = Wi0*ctx + Wh0 partials =================
    if (w < 8) {
      const int kb = w * 64;
      const float* xp = ctxt + (size_t)kb * BB + lane;
      float s0 = 0, s1 = 0, s2 = 0, s3 = 0, s4 = 0, s5 = 0;
#pragma unroll 8
      for (int k = 0; k < 64; k += 4) {
        float x0 = ldnt(xp + (k + 0) * BB);
        float x1 = ldnt(xp + (k + 1) * BB);
        float x2 = ldnt(xp + (k + 2) * BB);
        float x3 = ldnt(xp + (k + 3) * BB);
        float4 w0 = *(const float4*)&WL0[0][kb + k];
        float4 w1 = *(const float4*)&WL0[1][kb + k];
        float4 w2 = *(const float4*)&WL0[2][kb + k];
        float4 w3 = *(const float4*)&WL0[3][kb + k];
        float4 w4 = *(const float4*)&WL0[4][kb + k];
        float4 w5 = *(const float4*)&WL0[5][kb + k];
        s0 += w0.x * x0 + w0.y * x1 + w0.z * x2 + w0.w * x3;
        s1 += w1.x * x0 + w1.y * x1 + w1.z * x2 + w1.w * x3;
        s2 += w2.x * x0 + w2.y * x1 + w2.z * x2 + w2.w * x3;
        s3 += w3.x * x0 + w3.y * x1 + w3.z * x2 + w3.w * x3;
        s4 += w4.x * x0 + w4.y * x1 + w4.z * x2 + w4.w * x3;
        s5 += w5.x * x0 + w5.y * x1 + w5.z * x2 + w5.w * x3;
      }
      wi[0][w][lane] = s0; wi[1][w][lane] = s1;
      wi[2][w][lane] = s2; wi[3][w][lane] = s3;
      wi[4][w][lane] = s4; wi[5][w][lane] = s5;
    }
    __syncthreads();
    if (tid < 128) {
      int b = tid & 63, jj = tid >> 6, j = j0g + jj;
      float Ri = 0, Zi = 0, Ni = 0, Rh = 0, Zh = 0, Nh = 0;
#pragma unroll
      for (int q = 0; q < 8; ++q) {
        Ri += wi[jj][q][b]; Zi += wi[2 + jj][q][b]; Ni += wi[4 + jj][q][b];
      }
#pragma unroll
      for (int q = 0; q < 4; ++q) {
        Rh += wh0p[jj][q][b]; Zh += wh0p[2 + jj][q][b]; Nh += wh0p[4 + jj][q][b];
      }
      const float* gx = a.gixT + (size_t)t * G3 * BB;
      float gr = ldnt(&gx[(size_t)j * BB + b]);
      float gz = ldnt(&gx[(size_t)(j + 512) * BB + b]);
      float gn = ldnt(&gx[(size_t)(j + 1024) * BB + b]);
      float r = sigmoid_fast(gr + Ri + a.b_hh0[j] + Rh);
      float z = sigmoid_fast(gz + Zi + a.b_hh0[j + 512] + Zh);
      float n = tanh_fast(gn + Ni + r * (a.b_hh0[j + 1024] + Nh));
      float hold = ldnt(&h0p[(size_t)j * BB + b]);
      stg_sc(&h0n[(size_t)j * BB + b], (1.f - z) * n + z * hold);
    }
    gbar(a.bar, t * 4 + 2);

    // ================= phase delta: GRU1 = Wi1*h0n + Wh1 partials =================
    if (w < 8) {
      const int kb = w * 64;
      const float* xp = h0n + (size_t)kb * BB + lane;
      float s0 = 0, s1 = 0, s2 = 0, s3 = 0, s4 = 0, s5 = 0;
#pragma unroll 8
      for (int k = 0; k < 64; k += 4) {
        float x0 = ldnt(xp + (k + 0) * BB);
        float x1 = ldnt(xp + (k + 1) * BB);
        float x2 = ldnt(xp + (k + 2) * BB);
        float x3 = ldnt(xp + (k + 3) * BB);
        float4 w0 = *(const float4*)&WL1[0][kb + k];
        float4 w1 = *(const float4*)&WL1[1][kb + k];
        float4 w2 = *(const float4*)&WL1[2][kb + k];
        float4 w3 = *(const float4*)&WL1[3][kb + k];
        float4 w4 = *(const float4*)&WL1[4][kb + k];
        float4 w5 = *(const float4*)&WL1[5][kb + k];
        s0 += w0.x * x0 + w0.y * x1 + w0.z * x2 + w0.w * x3;
        s1 += w1.x * x0 + w1.y * x1 + w1.z * x2 + w1.w * x3;
        s2 += w2.x * x0 + w2.y * x1 + w2.z * x2 + w2.w * x3;
        s3 += w3.x * x0 + w3.y * x1 + w3.z * x2 + w3.w * x3;
        s4 += w4.x * x0 + w4.y * x1 + w4.z * x2 + w4.w * x3;
        s5 += w5.x * x0 + w5.y * x1 + w5.z * x2 + w5.w * x3;
      }
      wi[0][w][lane] = s0; wi[1][w][lane] = s1;
      wi[2][w][lane] = s2; wi[3][w][lane] = s3;
      wi[4][w][lane] = s4; wi[5][w][lane] = s5;
    }
    __syncthreads();
    if (tid < 128) {
      int b = tid & 63, jj = tid >> 6, j = j0g + jj;
      float Ri = 0, Zi = 0, Ni = 0, Rh = 0, Zh = 0, Nh = 0;
#pragma unroll
      for (int q = 0; q < 8; ++q) {
        Ri += wi[jj][q][b]; Zi += wi[2 + jj][q][b]; Ni += wi[4 + jj][q][b];
      }
#pragma unroll
      for (int q = 0; q < 4; ++q) {
        Rh += wh1p[jj][q][b]; Zh += wh1p[2 + jj][q][b]; Nh += wh1p[4 + jj][q][b];
      }
      float r = sigmoid_fast(a.b_ih1[j] + Ri + a.b_hh1[j] + Rh);
      float z = sigmoid_fast(a.b_ih1[j + 512] + Zi + a.b_hh1[j + 512] + Zh);
      float n = tanh_fast(a.b_ih1[j + 1024] + Ni + r * (a.b_hh1[j + 1024] + Nh));
      float hold = ldnt(&h1p[(size_t)j * BB + b]);
      float hv = (1.f - z) * n + z * hold;
      stg_sc(&h1n[(size_t)j * BB + b], hv);
      a.outsb[((size_t)t * BB + b) * HH + j] = __float2bfloat16(hv);
    }
    gbar(a.bar, t * 4 + 3);
  }
}

// ---------------- final dense: C[m,v] = A[m,:] . Bt[v,:] + bias[v], scatter to [B,T,V]
__global__ __launch_bounds__(256) void dense_kernel(const __hip_bfloat16* __restrict__ A,
                                                    const __hip_bfloat16* __restrict__ Bt,
                                                    const float* __restrict__ bias,
                                                    float* __restrict__ out) {
  __shared__ __align__(16) short As[128 * 64];
  __shared__ __align__(16) short Bs[128 * 64];
  int mt = blockIdx.x;         // 0..31
  int nt = blockIdx.y;         // 0..249
  int tid = threadIdx.x;
  int w = tid >> 6, lane = tid & 63;
  int wm = w >> 1, wn = w & 1;
  f32x4 acc[4][4];
#pragma unroll
  for (int m = 0; m < 4; ++m)
#pragma unroll
    for (int n = 0; n < 4; ++n) acc[m][n] = (f32x4)0.f;

  const short* Ag = (const short*)A + (size_t)(mt * 128) * 512;
  const short* Bg = (const short*)Bt + (size_t)(nt * 128) * 512;

  for (int kt = 0; kt < 8; ++kt) {
    int k0 = kt * 64;
#pragma unroll
    for (int c = 0; c < 4; ++c) {
      int chunk = w * 4 + c;                  // 0..15, wave-uniform
      int row = chunk * 8 + (lane >> 3);      // 0..127
      int col = (lane & 7) * 8;               // bf16 col within 64
      async16(As + chunk * 512, Ag + (size_t)row * 512 + k0 + col);
      async16(Bs + chunk * 512, Bg + (size_t)row * 512 + k0 + col);
    }
    __syncthreads();
#pragma unroll
    for (int kk = 0; kk < 2; ++kk) {
      int krow = kk * 32 + (lane >> 4) * 8;
      bf16x8 af[4], bf[4];
#pragma unroll
      for (int m = 0; m < 4; ++m) {
        int r = wm * 64 + m * 16 + (lane & 15);
        af[m] = *(const bf16x8*)&As[r * 64 + krow];
      }
#pragma unroll
      for (int n = 0; n < 4; ++n) {
        int r = wn * 64 + n * 16 + (lane & 15);
        bf[n] = *(const bf16x8*)&Bs[r * 64 + krow];
      }
#pragma unroll
      for (int m = 0; m < 4; ++m)
#pragma unroll
        for (int n = 0; n < 4; ++n)
          acc[m][n] = __builtin_amdgcn_mfma_f32_16x16x32_bf16(af[m], bf[n], acc[m][n], 0, 0, 0);
    }
    __syncthreads();
  }
#pragma unroll
  for (int m = 0; m < 4; ++m) {
    int rbase = mt * 128 + wm * 64 + m * 16 + (lane >> 4) * 4;
#pragma unroll
    for (int n = 0; n < 4; ++n) {
      int v = nt * 128 + wn * 64 + n * 16 + (lane & 15);
      float bv = bias[v];
#pragma unroll
      for (int r = 0; r < 4; ++r) {
        int mi = rbase + r;                  // mi = t*64 + b
        size_t off = (size_t)(mi & 63) * (TT * VV) + (size_t)(mi >> 6) * VV + v;
        out[off] = acc[m][n][r] + bv;
      }
    }
  }
}

extern "C" void kernel_launch(void* const* d_in, const int* in_sizes, int n_in,
                              void* d_out, int out_size, void* d_ws, size_t ws_size,
                              hipStream_t stream) {
  const int*   X     = (const int*)d_in[0];
  const float* enc   = (const float*)d_in[1];
  const float* hs    = (const float*)d_in[2];
  const int*   vlen  = (const int*)d_in[3];
  const float* emb   = (const float*)d_in[4];
  const float* Wq    = (const float*)d_in[5];
  const float* Wk    = (const float*)d_in[6];
  const float* wv    = (const float*)d_in[7];
  const float* W_ih0 = (const float*)d_in[8];
  const float* W_hh0 = (const float*)d_in[9];
  const float* b_ih0 = (const float*)d_in[10];
  const float* b_hh0 = (const float*)d_in[11];
  const float* W_ih1 = (const float*)d_in[12];
  const float* W_hh1 = (const float*)d_in[13];
  const float* b_ih1 = (const float*)d_in[14];
  const float* b_hh1 = (const float*)d_in[15];
  const float* dW    = (const float*)d_in[16];
  const float* db    = (const float*)d_in[17];
  float* out = (float*)d_out;

  char* wp = (char*)d_ws;
  auto alloc = [&](size_t bytes) { char* p = wp; wp += (bytes + 255) & ~(size_t)255; return p; };
  __hip_bfloat16* dWb   = (__hip_bfloat16*)alloc((size_t)VV * HH * 2);
  __hip_bfloat16* outsb = (__hip_bfloat16*)alloc((size_t)TT * BB * HH * 2);
  float* keysp = (float*)alloc((size_t)BB * SS * HH * 4);
  float* gixT  = (float*)alloc((size_t)TT * G3 * BB * 4);
  float* WkT   = (float*)alloc((size_t)HH * HH * 4);
  float* WT0e  = (float*)alloc((size_t)EE * G3 * 4);
  float* h0T   = (float*)alloc((size_t)HH * BB * 4);
  float* h1T   = (float*)alloc((size_t)HH * BB * 4);
  float* qS    = (float*)alloc((size_t)TT * BB * HH * 4);
  float* ctxS  = (float*)alloc((size_t)TT * STSZ * 4);
  float* h0S   = (float*)alloc((size_t)TT * STSZ * 4);
  float* h1S   = (float*)alloc((size_t)TT * STSZ * 4);
  int*   bar   = (int*)alloc(TT * 4 * sizeof(int));

  hipMemsetAsync(bar, 0, TT * 4 * sizeof(int), stream);

  dim3 tb(32, 8);
  // WkT[h][n] = Wk[n][h]
  transpose_kernel<<<dim3(HH / 32, HH / 32), tb, 0, stream>>>(WkT, Wk, HH, HH, HH, 0);
  // WT0e[e][n] = W_ih0[n][512+e]  (emb part of W_ih0, ld=768)
  transpose_kernel<<<dim3(EE / 32, G3 / 32), tb, 0, stream>>>(WT0e, W_ih0, G3, EE, HH + EE, HH);
  cast_kernel<<<2048, 256, 0, stream>>>(dW, dWb, VV * HH);
  hsT_kernel<<<128, 256, 0, stream>>>(hs, h0T, h1T);

  // keysp[b*S+s][n] = enc row . WkT   (M=4096,N=512,K=512)
  gemm32_kernel<<<dim3(BB * SS / 64, HH / 128), 256, 0, stream>>>(
      enc, nullptr, WkT, nullptr, keysp, HH, HH, HH, 0);
  // gixT[t][n][b] = emb[X[b,t]] . WT0e + b_ih0   (M=4096,N=1536,K=256, tb-major out)
  gemm32_kernel<<<dim3(TT * BB / 64, G3 / 128), 256, 0, stream>>>(
      emb, X, WT0e, b_ih0, gixT, G3, EE, G3, 1);

  RecArgs args;
  args.Wq = Wq; args.W_ih0 = W_ih0; args.W_hh0 = W_hh0; args.W_ih1 = W_ih1; args.W_hh1 = W_hh1;
  args.b_hh0 = b_hh0; args.b_ih1 = b_ih1; args.b_hh1 = b_hh1;
  args.gixT = gixT; args.keysp = keysp; args.enc = enc; args.wv = wv; args.vlen = vlen;
  args.h0init = h0T; args.h1init = h1T;
  args.qS = qS; args.ctxS = ctxS; args.h0S = h0S; args.h1S = h1S;
  args.bar = bar; args.outsb = outsb;
  void* kp[] = {&args};
  hipLaunchCooperativeKernel(reinterpret_cast<void*>(recurrent_kernel),
                             dim3(NBLK), dim3(1024), kp, 0, stream);

  dense_kernel<<<dim3(32, 250), 256, 0, stream>>>(outsb, dWb, db, out);
}

// Round 8
// 4428.650 us; speedup vs baseline: 1.3794x; 1.3794x over previous
//
#include <hip/hip_runtime.h>
#include <hip/hip_bf16.h>

#define VV 32000
#define EE 256
#define HH 512
#define BB 64
#define TT 64
#define SS 64
#define G3 1536   // 3*H
#define NBLK 256
#define STSZ (HH * BB)   // one state buffer, floats

typedef __attribute__((ext_vector_type(8))) short bf16x8;
typedef __attribute__((ext_vector_type(4))) float f32x4;

__device__ __forceinline__ void async16(void* lds, const void* g) {
  __builtin_amdgcn_global_load_lds((const __attribute__((address_space(1))) void*)g,
                                   (__attribute__((address_space(3))) void*)lds, 16, 0, 0);
}

__device__ __forceinline__ float sigmoid_fast(float x) {
  return 1.0f / (1.0f + __expf(-x));
}
__device__ __forceinline__ float tanh_fast(float x) {
  x = fminf(fmaxf(x, -15.f), 15.f);
  float e = __expf(2.f * x);
  return (e - 1.f) / (e + 1.f);
}

// coherent store: write-through past L2 to the IF coherence point (no fence needed)
__device__ __forceinline__ void stg_sc(float* p, float v) {
  asm volatile("global_store_dword %0, %1, off sc0 sc1" :: "v"(p), "v"(v) : "memory");
}
__device__ __forceinline__ void stg_sci(int* p, int v) {
  asm volatile("global_store_dword %0, %1, off sc0 sc1" :: "v"(p), "v"(v) : "memory");
}
__device__ __forceinline__ int ld_agent(const int* p) {
  return __hip_atomic_load(p, __ATOMIC_RELAXED, __HIP_MEMORY_SCOPE_AGENT);
}

// fence-free grid barrier, flag/master/broadcast form.
// Arrival: each block stores `phase` to its own flag (no RMW contention).
// Block 0 wave 0 polls all 256 flags (64 lanes x 4), then stores `go`.
// Other blocks poll only `go`. phase is monotonic 1.. within the launch;
// flags/go are memset to 0 at launch start (graph-captured, per replay).
__device__ __forceinline__ void gbar(int* flags, int* go, int phase) {
  __syncthreads();   // drains vmcnt per wave -> this block's sc stores are at IF
  if (blockIdx.x == 0) {
    if (threadIdx.x < 64) {
      const int l = threadIdx.x;
      if (l == 0) stg_sci(&flags[0], phase);
      for (;;) {
        int f0 = ld_agent(&flags[l]);
        int f1 = ld_agent(&flags[l + 64]);
        int f2 = ld_agent(&flags[l + 128]);
        int f3 = ld_agent(&flags[l + 192]);
        bool ok = (f0 >= phase) && (f1 >= phase) && (f2 >= phase) && (f3 >= phase);
        if (__all(ok)) break;
        __builtin_amdgcn_s_sleep(1);
      }
      if (l == 0) stg_sci(go, phase);
    }
  } else {
    if (threadIdx.x == 0) {
      stg_sci(&flags[blockIdx.x], phase);
      while (ld_agent(go) < phase) __builtin_amdgcn_s_sleep(1);
    }
  }
  __syncthreads();
}

// ---------------- strided 2D transpose: dst[c][r] = src[r*ld + off + c]
__global__ __launch_bounds__(256) void transpose_kernel(float* __restrict__ dst,
                                                        const float* __restrict__ src,
                                                        int R, int C, int ld, int off) {
  __shared__ float tile[32][33];
  int c0 = blockIdx.x * 32, r0 = blockIdx.y * 32;
  int x = threadIdx.x, y = threadIdx.y;     // block (32,8)
  for (int i = y; i < 32; i += 8) tile[i][x] = src[(size_t)(r0 + i) * ld + off + c0 + x];
  __syncthreads();
  for (int i = y; i < 32; i += 8) dst[(size_t)(c0 + i) * R + r0 + x] = tile[x][i];
}

// ---------------- fp32 -> bf16 cast
__global__ __launch_bounds__(256) void cast_kernel(const float* __restrict__ src,
                                                   __hip_bfloat16* __restrict__ dst, int n) {
  for (int i = blockIdx.x * blockDim.x + threadIdx.x; i < n; i += gridDim.x * blockDim.x)
    dst[i] = __float2bfloat16(src[i]);
}

// ---------------- transpose initial hidden state into [h][b] layout
__global__ __launch_bounds__(256) void hsT_kernel(const float* __restrict__ hs,
                                                  float* __restrict__ h0T,
                                                  float* __restrict__ h1T) {
  int i = blockIdx.x * 256 + threadIdx.x;   // 0..32767
  int b = i >> 9, h = i & 511;
  h0T[h * BB + b] = hs[b * HH + h];
  h1T[h * BB + b] = hs[BB * HH + b * HH + h];
}

// ---------------- tiled fp32 GEMM: C = A(row-gathered) * Bk (+bias)
// tbmaj==0: C[m][n];  tbmaj==1: C[(m>>6)][n][m&63]  (i.e. [t][n][b] for m=t*64+b)
__global__ __launch_bounds__(256) void gemm32_kernel(const float* __restrict__ A,
                                                     const int* __restrict__ Xtb,
                                                     const float* __restrict__ Bk,
                                                     const float* __restrict__ bias,
                                                     float* __restrict__ C,
                                                     int N, int K, int ldb, int tbmaj) {
  __shared__ float Xs[32][65];    // [k][m]
  __shared__ float Ws[32][129];   // [k][n]
  __shared__ int toks[64];
  int m0 = blockIdx.x * 64, n0 = blockIdx.y * 128;
  int tid = threadIdx.x;
  if (tid < 64) {
    int m = m0 + tid;
    toks[tid] = Xtb ? Xtb[(m & 63) * TT + (m >> 6)] : m;
  }
  __syncthreads();
  float acc[4][8];
#pragma unroll
  for (int i = 0; i < 4; ++i)
#pragma unroll
    for (int j = 0; j < 8; ++j) acc[i][j] = 0.f;
  int mi = (tid >> 4) * 4;   // 4 m per thread
  int ni = (tid & 15) * 8;   // 8 n per thread
  for (int kc = 0; kc < K; kc += 32) {
#pragma unroll
    for (int i = 0; i < 16; ++i) {
      int idx = tid + i * 256;          // 0..4095
      int kk = idx >> 7, nn = idx & 127;
      Ws[kk][nn] = Bk[(size_t)(kc + kk) * ldb + n0 + nn];
    }
#pragma unroll
    for (int i = 0; i < 8; ++i) {
      int idx = tid + i * 256;          // 0..2047
      int mm = idx >> 5, kk = idx & 31;
      Xs[kk][mm] = A[(size_t)toks[mm] * K + kc + kk];
    }
    __syncthreads();
#pragma unroll
    for (int k = 0; k < 32; ++k) {
      float xv[4], wv[8];
#pragma unroll
      for (int i = 0; i < 4; ++i) xv[i] = Xs[k][mi + i];
#pragma unroll
      for (int j = 0; j < 8; ++j) wv[j] = Ws[k][ni + j];
#pragma unroll
      for (int i = 0; i < 4; ++i)
#pragma unroll
        for (int j = 0; j < 8; ++j) acc[i][j] += xv[i] * wv[j];
    }
    __syncthreads();
  }
#pragma unroll
  for (int i = 0; i < 4; ++i) {
    int m = m0 + mi + i;
#pragma unroll
    for (int j = 0; j < 8; ++j) {
      int n = n0 + ni + j;
      float v = acc[i][j] + (bias ? bias[n] : 0.f);
      if (tbmaj) C[((size_t)(m >> 6) * N + n) * BB + (m & 63)] = v;
      else       C[(size_t)m * N + n] = v;
    }
  }
}

// ---------------- persistent recurrent kernel (256 blocks x 512 threads)
// Block blk owns output cols j0=2*blk, j0+1 (q, h0, h1). Wq/GRU weight slices
// LDS-resident. State in [k][b] one-shot per-step buffers, sc0sc1 stores, plain
// cached reads. keysp/enc/gixT stay L2-resident. 4 flag-barriers per step.
struct RecArgs {
  const float *Wq, *W_ih0, *W_hh0, *W_ih1, *W_hh1;
  const float *b_hh0, *b_ih1, *b_hh1;
  const float *gixT, *keysp, *enc, *wv;   // gixT: [t][j(1536)][b]
  const int* vlen;
  const float *h0init, *h1init;     // [k][b]
  float *qS;                        // [TT][b][j]  one-shot
  float *ctxS, *h0S, *h1S;          // [TT][k][b]  one-shot
  int *flags, *go;
  __hip_bfloat16* outsb;
};

// one GRU layer: waves 0-3 accumulate Wi*x, waves 4-7 accumulate Wh*h (k-split).
template <int LAYER>
__device__ __forceinline__ void gru_phase(const RecArgs& a, const float (*WL)[1024],
                                          const float* __restrict__ X,
                                          const float* __restrict__ Hp,
                                          float* __restrict__ Hn,
                                          const float* __restrict__ biasI,  // L0: gixT slice, L1: b_ih1
                                          const float* __restrict__ bhh, int t,
                                          int j0, int w, int lane, int tid,
                                          float (*red)[8][64]) {
  const float* xb = (w < 4) ? X : Hp;
  const int kb = (w & 3) * 128;
  const int wk = (w < 4) ? kb : 512 + kb;
  float s0 = 0, s1 = 0, s2 = 0, s3 = 0, s4 = 0, s5 = 0;
#pragma unroll 8
  for (int k = 0; k < 128; k += 4) {
    float x0 = xb[(kb + k) * BB + lane];
    float x1 = xb[(kb + k + 1) * BB + lane];
    float x2 = xb[(kb + k + 2) * BB + lane];
    float x3 = xb[(kb + k + 3) * BB + lane];
    float4 w0 = *(const float4*)&WL[0][wk + k];
    float4 w1 = *(const float4*)&WL[1][wk + k];
    float4 w2 = *(const float4*)&WL[2][wk + k];
    float4 w3 = *(const float4*)&WL[3][wk + k];
    float4 w4 = *(const float4*)&WL[4][wk + k];
    float4 w5 = *(const float4*)&WL[5][wk + k];
    s0 += w0.x * x0 + w0.y * x1 + w0.z * x2 + w0.w * x3;
    s1 += w1.x * x0 + w1.y * x1 + w1.z * x2 + w1.w * x3;
    s2 += w2.x * x0 + w2.y * x1 + w2.z * x2 + w2.w * x3;
    s3 += w3.x * x0 + w3.y * x1 + w3.z * x2 + w3.w * x3;
    s4 += w4.x * x0 + w4.y * x1 + w4.z * x2 + w4.w * x3;
    s5 += w5.x * x0 + w5.y * x1 + w5.z * x2 + w5.w * x3;
  }
  red[0][w][lane] = s0; red[1][w][lane] = s1;
  red[2][w][lane] = s2; red[3][w][lane] = s3;
  red[4][w][lane] = s4; red[5][w][lane] = s5;
  __syncthreads();
  if (tid < 128) {
    int b = tid & 63, jj = tid >> 6, j = j0 + jj;
    float Ri = 0, Rh = 0, Zi = 0, Zh = 0, Ni = 0, Nh = 0;
#pragma unroll
    for (int q = 0; q < 4; ++q) {
      Ri += red[jj][q][b];     Rh += red[jj][4 + q][b];
      Zi += red[2 + jj][q][b]; Zh += red[2 + jj][4 + q][b];
      Ni += red[4 + jj][q][b]; Nh += red[4 + jj][4 + q][b];
    }
    float gr, gz, gn;
    if (LAYER == 0) {
      gr = biasI[(size_t)j * BB + b];
      gz = biasI[(size_t)(j + 512) * BB + b];
      gn = biasI[(size_t)(j + 1024) * BB + b];
    } else {
      gr = biasI[j]; gz = biasI[j + 512]; gn = biasI[j + 1024];
    }
    float r = sigmoid_fast(gr + Ri + bhh[j] + Rh);
    float z = sigmoid_fast(gz + Zi + bhh[j + 512] + Zh);
    float n = tanh_fast(gn + Ni + r * (bhh[j + 1024] + Nh));
    float hold = Hp[j * BB + b];
    float hv = (1.f - z) * n + z * hold;
    stg_sc(&Hn[j * BB + b], hv);
    if (LAYER == 1) a.outsb[((size_t)t * BB + b) * HH + j] = __float2bfloat16(hv);
  }
}

__global__ __launch_bounds__(512) void recurrent_kernel(RecArgs a) {
  const int blk = blockIdx.x, tid = threadIdx.x;
  const int w = tid >> 6, lane = tid & 63;
  const int j0 = 2 * blk;

  __shared__ __align__(16) float WL0[6][1024];   // slots r0,r1,z0,z1,n0,n1; k<512 Wi, k>=512 Wh
  __shared__ __align__(16) float WL1[6][1024];
  __shared__ __align__(16) float QL[2][512];     // Wq rows j0, j0+1
  __shared__ float red[6][8][64];
  __shared__ float sQ[HH], sWV[HH], sAttn[SS];

  // one-time weight preload (rows of original matrices are contiguous)
  for (int idx = tid; idx < 6 * 1024; idx += 512) {
    int s = idx >> 10, k = idx & 1023;
    int g = s >> 1, jj = s & 1;
    int r = g * 512 + j0 + jj;
    WL0[s][k] = (k < 512) ? a.W_ih0[(size_t)r * 768 + k] : a.W_hh0[(size_t)r * 512 + (k - 512)];
    WL1[s][k] = (k < 512) ? a.W_ih1[(size_t)r * 512 + k] : a.W_hh1[(size_t)r * 512 + (k - 512)];
  }
  for (int idx = tid; idx < 1024; idx += 512) {
    int jj = idx >> 9, k = idx & 511;
    QL[jj][k] = a.Wq[(size_t)(j0 + jj) * HH + k];
  }
  sWV[tid] = a.wv[tid];
  const int vl = (blk < BB) ? a.vlen[blk] : 0;
  __syncthreads();

  for (int t = 0; t < TT; ++t) {
    const float* h0p = (t == 0) ? a.h0init : a.h0S + (size_t)(t - 1) * STSZ;
    const float* h1p = (t == 0) ? a.h1init : a.h1S + (size_t)(t - 1) * STSZ;
    float* qrowT = a.qS + (size_t)t * BB * HH;   // [b][j]
    float* ctxt = a.ctxS + (size_t)t * STSZ;
    float* h0n  = a.h0S + (size_t)t * STSZ;
    float* h1n  = a.h1S + (size_t)t * STSZ;

    // ---- P0: q[b][j0..j0+1] = h1p[b,:] . Wq[j,:]  (j-distributed, k-split 8 waves) ----
    {
      const float* xk = h1p + (size_t)(w * 64) * BB;
      float q0 = 0.f, q1 = 0.f;
#pragma unroll 8
      for (int k = 0; k < 64; ++k) {
        float x = xk[k * BB + lane];
        q0 += QL[0][w * 64 + k] * x;
        q1 += QL[1][w * 64 + k] * x;
      }
      red[0][w][lane] = q0; red[1][w][lane] = q1;
      __syncthreads();
      if (tid < 64) {
        int b = tid;
        float v0 = 0.f, v1 = 0.f;
#pragma unroll
        for (int q = 0; q < 8; ++q) { v0 += red[0][q][b]; v1 += red[1][q][b]; }
        stg_sc(&qrowT[(size_t)b * HH + j0], v0);
        stg_sc(&qrowT[(size_t)b * HH + j0 + 1], v1);
      }
    }
    gbar(a.flags, a.go, t * 4 + 1);

    // ---- P1: scores + softmax + context (blocks 0..63, b = blk) ----
    if (blk < BB) {
      const int b = blk;
      sQ[tid] = qrowT[(size_t)b * HH + tid];   // coalesced 2KB, one-shot
      __syncthreads();
      for (int s = w; s < SS; s += 8) {
        const float* kp = a.keysp + ((size_t)b * SS + s) * HH;
        float p = 0.f;
#pragma unroll
        for (int h = lane; h < HH; h += 64)
          p += tanh_fast(sQ[h] + kp[h]) * sWV[h];
#pragma unroll
        for (int off = 32; off > 0; off >>= 1) p += __shfl_down(p, off);
        if (lane == 0) sAttn[s] = (s < vl) ? p : -1e6f;
      }
      __syncthreads();
      if (w == 0) {
        float v = sAttn[lane];
        float mx = v;
        for (int off = 32; off > 0; off >>= 1) mx = fmaxf(mx, __shfl_xor(mx, off));
        float e = __expf(v - mx);
        float sm = e;
        for (int off = 32; off > 0; off >>= 1) sm += __shfl_xor(sm, off);
        sAttn[lane] = e / sm;
      }
      __syncthreads();
      float c = 0.f;
#pragma unroll 8
      for (int s = 0; s < SS; ++s) c += sAttn[s] * a.enc[((size_t)b * SS + s) * HH + tid];
      stg_sc(&ctxt[(size_t)tid * BB + b], c);
    }
    gbar(a.flags, a.go, t * 4 + 2);

    // ---- P2: GRU layer 0 -> h0n ----
    gru_phase<0>(a, WL0, ctxt, h0p, h0n,
                 a.gixT + (size_t)t * G3 * BB, a.b_hh0, t, j0, w, lane, tid, red);
    gbar(a.flags, a.go, t * 4 + 3);

    // ---- P3: GRU layer 1 -> h1n (+ bf16 outs) ----
    gru_phase<1>(a, WL1, h0n, h1p, h1n,
                 a.b_ih1, a.b_hh1, t, j0, w, lane, tid, red);
    gbar(a.flags, a.go, t * 4 + 4);
  }
}

// ---------------- final dense: C[m,v] = A[m,:] . Bt[v,:] + bias[v], scatter to [B,T,V]
__global__ __launch_bounds__(256) void dense_kernel(const __hip_bfloat16* __restrict__ A,
                                                    const __hip_bfloat16* __restrict__ Bt,
                                                    const float* __restrict__ bias,
                                                    float* __restrict__ out) {
  __shared__ __align__(16) short As[128 * 64];
  __shared__ __align__(16) short Bs[128 * 64];
  int mt = blockIdx.x;         // 0..31
  int nt = blockIdx.y;         // 0..249
  int tid = threadIdx.x;
  int w = tid >> 6, lane = tid & 63;
  int wm = w >> 1, wn = w & 1;
  f32x4 acc[4][4];
#pragma unroll
  for (int m = 0; m < 4; ++m)
#pragma unroll
    for (int n = 0; n < 4; ++n) acc[m][n] = (f32x4)0.f;

  const short* Ag = (const short*)A + (size_t)(mt * 128) * 512;
  const short* Bg = (const short*)Bt + (size_t)(nt * 128) * 512;

  for (int kt = 0; kt < 8; ++kt) {
    int k0 = kt * 64;
#pragma unroll
    for (int c = 0; c < 4; ++c) {
      int chunk = w * 4 + c;                  // 0..15, wave-uniform
      int row = chunk * 8 + (lane >> 3);      // 0..127
      int col = (lane & 7) * 8;               // bf16 col within 64
      async16(As + chunk * 512, Ag + (size_t)row * 512 + k0 + col);
      async16(Bs + chunk * 512, Bg + (size_t)row * 512 + k0 + col);
    }
    __syncthreads();
#pragma unroll
    for (int kk = 0; kk < 2; ++kk) {
      int krow = kk * 32 + (lane >> 4) * 8;
      bf16x8 af[4], bf[4];
#pragma unroll
      for (int m = 0; m < 4; ++m) {
        int r = wm * 64 + m * 16 + (lane & 15);
        af[m] = *(const bf16x8*)&As[r * 64 + krow];
      }
#pragma unroll
      for (int n = 0; n < 4; ++n) {
        int r = wn * 64 + n * 16 + (lane & 15);
        bf[n] = *(const bf16x8*)&Bs[r * 64 + krow];
      }
#pragma unroll
      for (int m = 0; m < 4; ++m)
#pragma unroll
        for (int n = 0; n < 4; ++n)
          acc[m][n] = __builtin_amdgcn_mfma_f32_16x16x32_bf16(af[m], bf[n], acc[m][n], 0, 0, 0);
    }
    __syncthreads();
  }
#pragma unroll
  for (int m = 0; m < 4; ++m) {
    int rbase = mt * 128 + wm * 64 + m * 16 + (lane >> 4) * 4;
#pragma unroll
    for (int n = 0; n < 4; ++n) {
      int v = nt * 128 + wn * 64 + n * 16 + (lane & 15);
      float bv = bias[v];
#pragma unroll
      for (int r = 0; r < 4; ++r) {
        int mi = rbase + r;                  // mi = t*64 + b
        size_t off = (size_t)(mi & 63) * (TT * VV) + (size_t)(mi >> 6) * VV + v;
        out[off] = acc[m][n][r] + bv;
      }
    }
  }
}

extern "C" void kernel_launch(void* const* d_in, const int* in_sizes, int n_in,
                              void* d_out, int out_size, void* d_ws, size_t ws_size,
                              hipStream_t stream) {
  const int*   X     = (const int*)d_in[0];
  const float* enc   = (const float*)d_in[1];
  const float* hs    = (const float*)d_in[2];
  const int*   vlen  = (const int*)d_in[3];
  const float* emb   = (const float*)d_in[4];
  const float* Wq    = (const float*)d_in[5];
  const float* Wk    = (const float*)d_in[6];
  const float* wv    = (const float*)d_in[7];
  const float* W_ih0 = (const float*)d_in[8];
  const float* W_hh0 = (const float*)d_in[9];
  const float* b_ih0 = (const float*)d_in[10];
  const float* b_hh0 = (const float*)d_in[11];
  const float* W_ih1 = (const float*)d_in[12];
  const float* W_hh1 = (const float*)d_in[13];
  const float* b_ih1 = (const float*)d_in[14];
  const float* b_hh1 = (const float*)d_in[15];
  const float* dW    = (const float*)d_in[16];
  const float* db    = (const float*)d_in[17];
  float* out = (float*)d_out;

  char* wp = (char*)d_ws;
  auto alloc = [&](size_t bytes) { char* p = wp; wp += (bytes + 255) & ~(size_t)255; return p; };
  __hip_bfloat16* dWb   = (__hip_bfloat16*)alloc((size_t)VV * HH * 2);
  __hip_bfloat16* outsb = (__hip_bfloat16*)alloc((size_t)TT * BB * HH * 2);
  float* keysp = (float*)alloc((size_t)BB * SS * HH * 4);
  float* gixT  = (float*)alloc((size_t)TT * G3 * BB * 4);
  float* WkT   = (float*)alloc((size_t)HH * HH * 4);
  float* WT0e  = (float*)alloc((size_t)EE * G3 * 4);
  float* h0T   = (float*)alloc((size_t)HH * BB * 4);
  float* h1T   = (float*)alloc((size_t)HH * BB * 4);
  float* qS    = (float*)alloc((size_t)TT * BB * HH * 4);
  float* ctxS  = (float*)alloc((size_t)TT * STSZ * 4);
  float* h0S   = (float*)alloc((size_t)TT * STSZ * 4);
  float* h1S   = (float*)alloc((size_t)TT * STSZ * 4);
  int*   flags = (int*)alloc(NBLK * sizeof(int));
  int*   go    = (int*)alloc(64 * sizeof(int));

  hipMemsetAsync(flags, 0, NBLK * sizeof(int), stream);
  hipMemsetAsync(go, 0, 64 * sizeof(int), stream);

  dim3 tb(32, 8);
  // WkT[h][n] = Wk[n][h]
  transpose_kernel<<<dim3(HH / 32, HH / 32), tb, 0, stream>>>(WkT, Wk, HH, HH, HH, 0);
  // WT0e[e][n] = W_ih0[n][512+e]  (emb part of W_ih0, ld=768)
  transpose_kernel<<<dim3(EE / 32, G3 / 32), tb, 0, stream>>>(WT0e, W_ih0, G3, EE, HH + EE, HH);
  cast_kernel<<<2048, 256, 0, stream>>>(dW, dWb, VV * HH);
  hsT_kernel<<<128, 256, 0, stream>>>(hs, h0T, h1T);

  // keysp[b*S+s][n] = enc row . WkT   (M=4096,N=512,K=512)
  gemm32_kernel<<<dim3(BB * SS / 64, HH / 128), 256, 0, stream>>>(
      enc, nullptr, WkT, nullptr, keysp, HH, HH, HH, 0);
  // gixT[t][n][b] = emb[X[b,t]] . WT0e + b_ih0   (M=4096,N=1536,K=256, tb-major out)
  gemm32_kernel<<<dim3(TT * BB / 64, G3 / 128), 256, 0, stream>>>(
      emb, X, WT0e, b_ih0, gixT, G3, EE, G3, 1);

  RecArgs args;
  args.Wq = Wq; args.W_ih0 = W_ih0; args.W_hh0 = W_hh0; args.W_ih1 = W_ih1; args.W_hh1 = W_hh1;
  args.b_hh0 = b_hh0; args.b_ih1 = b_ih1; args.b_hh1 = b_hh1;
  args.gixT = gixT; args.keysp = keysp; args.enc = enc; args.wv = wv; args.vlen = vlen;
  args.h0init = h0T; args.h1init = h1T;
  args.qS = qS; args.ctxS = ctxS; args.h0S = h0S; args.h1S = h1S;
  args.flags = flags; args.go = go; args.outsb = outsb;
  void* kp[] = {&args};
  hipLaunchCooperativeKernel(reinterpret_cast<void*>(recurrent_kernel),
                             dim3(NBLK), dim3(512), kp, 0, stream);

  dense_kernel<<<dim3(32, 250), 256, 0, stream>>>(outsb, dWb, db, out);
}